// Round 7
// baseline (222.534 us; speedup 1.0000x reference)
//
#include <hip/hip_runtime.h>
#include <math.h>
#include <stdint.h>

// Problem constants
#define B_   128
#define K_   4
#define HW_  65536              // 256*256

constexpr int BLOCK  = 256;
constexpr int NC     = 16;                  // chunks per b
constexpr int CHUNK  = HW_ / NC;            // 4096 floats per stream per block
constexpr int STAGE  = BLOCK * 4;           // 1024 floats per stream per stage
constexpr int NSTAGE = CHUNK / STAGE;       // 4 stages

typedef float vfloat4 __attribute__((ext_vector_type(4)));

// Fire-and-forget global->LDS DMA, 16 B per lane (global_load_lds_dwordx4).
// LDS dest is wave-uniform base + lane*16 (m104); global addr is per-lane.
// CK-style addrspace casts via uintptr_t (AS1 is identity-mapped in flat
// space; AS3 pointer value = low 32 bits = LDS byte offset).
__device__ __forceinline__ void dma16(const float* g, float* l) {
    __builtin_amdgcn_global_load_lds(
        (__attribute__((address_space(1))) void*)(uintptr_t)(void*)(const_cast<float*>(g)),
        (__attribute__((address_space(3))) void*)(uint32_t)(uintptr_t)(void*)l,
        16, 0, 0);
}

// Per-element math (t is exactly 0.0 or 1.0):
//   s   = sigmoid(x)
//   pt  = t*s + (1-t)*(1-s) = fma(t, 1-2s, s)   (true-class probability)
//   bce = -ln(pt); exp(-bce) == pt
//   focal += ALPHA * (1-pt)^2 * bce
// Native v_exp/v_rcp/v_log — rel err ~1e-6, threshold is 0.11.
__device__ __forceinline__ void proc_elem(float x, float t,
                                          float& fs, float& in, float& ps,
                                          float& i2, float& ms) {
    float e   = __expf(-fabsf(x));                 // e^{-|x|}
    float inv = __builtin_amdgcn_rcpf(1.0f + e);   // sigmoid(|x|)
    bool  pos = (x >= 0.0f);
    float s   = pos ? inv : 1.0f - inv;            // sigmoid(x)
    float nms = fmaf(-2.0f, s, 1.0f);              // 1 - 2s
    float pt  = fmaf(t, nms, s);                   // prob of true class
    float l   = __logf(pt);                        // ln(pt) = -bce
    float om  = 1.0f - pt;
    fs = fmaf(om * om * l, -0.8f, fs);             // += ALPHA*(1-pt)^2*bce
    float pc  = fminf(fmaxf(s, 1e-4f), 0.9999f);   // clip(sigmoid) -> v_med3
    ps += pc;
    in  = fmaf(pc, t, in);
    float m = pos ? 1.0f : 0.0f;                   // mask (x >= 0)
    ms += m;
    i2  = fmaf(m, t, i2);
}

__device__ __forceinline__ void proc4(const vfloat4& xv, const vfloat4& tv,
                                      float& fs, float& in, float& ps,
                                      float& i2, float& ms) {
    proc_elem(xv.x, tv.x, fs, in, ps, i2, ms);
    proc_elem(xv.y, tv.y, fs, in, ps, i2, ms);
    proc_elem(xv.z, tv.z, fs, in, ps, i2, ms);
    proc_elem(xv.w, tv.w, fs, in, ps, i2, ms);
}

// Fused-K with double-buffered LDS staging via global_load_lds:
// per stage each wave issues 5 fire-and-forget DMA instructions (t + 4 masks,
// 1 KB each) and computes the PREVIOUS stage from LDS. Consumption is fully
// decoupled from the VMEM return path (no VGPR load-use chains). One
// __syncthreads per stage: its compiler-inserted vmcnt(0) drains exactly the
// previous stage's DMA; the next stage's DMA is issued after the barrier and
// overlaps this stage's compute. LDS 2*5*4KB = 40 KB -> 4 blocks/CU,
// 80 KB/CU outstanding DMA in steady state.
__global__ __launch_bounds__(BLOCK, 4) void partial_kernel(
    const float* __restrict__ pred_masks,   // B*K*HW
    const float* __restrict__ targets,      // B*HW
    float* __restrict__ fsum,               // B*K
    float* __restrict__ inter,              // B*K
    float* __restrict__ psum,               // B*K
    float* __restrict__ i2s,                // B*K
    float* __restrict__ msum,               // B*K
    float* __restrict__ tsum)               // B
{
    __shared__ float lds[2][5][STAGE];      // 40 KB

    const int blk = blockIdx.x;
    const int c   = blk & (NC - 1);
    const int b   = blk >> 4;               // NC == 16

    const float* tb = targets    + (size_t)b * HW_ + c * CHUNK;
    const float* xb = pred_masks + (size_t)b * K_ * HW_ + c * CHUNK;

    const int tid  = threadIdx.x;
    const int wave = tid >> 6;
    const int lane = tid & 63;
    const int off0 = tid * 4;               // == wave*256 + lane*4 (float idx)
    float* ldst0 = &lds[0][0][0];           // keep array provenance alive
    (void)ldst0;

    // Prologue: stage 0 -> buffer 0.
    {
        dma16(tb + off0,            &lds[0][0][wave * 256]);
        dma16(xb + off0,            &lds[0][1][wave * 256]);
        dma16(xb + HW_ + off0,      &lds[0][2][wave * 256]);
        dma16(xb + 2 * HW_ + off0,  &lds[0][3][wave * 256]);
        dma16(xb + 3 * HW_ + off0,  &lds[0][4][wave * 256]);
    }

    float fs[K_] = {0.f, 0.f, 0.f, 0.f};
    float in[K_] = {0.f, 0.f, 0.f, 0.f};
    float ps[K_] = {0.f, 0.f, 0.f, 0.f};
    float i2[K_] = {0.f, 0.f, 0.f, 0.f};
    float ms[K_] = {0.f, 0.f, 0.f, 0.f};
    float ts = 0.f;

    #pragma unroll
    for (int s = 0; s < NSTAGE; ++s) {
        // Drains vmcnt -> stage s DMA complete; also fences buffer reuse
        // (compute of stage s-1 finished before stage s+1 overwrote its buf).
        __syncthreads();
        const int buf  = s & 1;
        const int nbuf = buf ^ 1;
        if (s + 1 < NSTAGE) {               // compile-time resolved (unrolled)
            const int gof = (s + 1) * STAGE + off0;
            dma16(tb + gof,            &lds[nbuf][0][wave * 256]);
            dma16(xb + gof,            &lds[nbuf][1][wave * 256]);
            dma16(xb + HW_ + gof,      &lds[nbuf][2][wave * 256]);
            dma16(xb + 2 * HW_ + gof,  &lds[nbuf][3][wave * 256]);
            dma16(xb + 3 * HW_ + gof,  &lds[nbuf][4][wave * 256]);
        }
        const vfloat4 tv = *(const vfloat4*)&lds[buf][0][off0];
        ts += tv.x + tv.y + tv.z + tv.w;
        #pragma unroll
        for (int k = 0; k < K_; ++k) {
            const vfloat4 xv = *(const vfloat4*)&lds[buf][1 + k][off0];
            proc4(xv, tv, fs[k], in[k], ps[k], i2[k], ms[k]);
        }
    }

    // Pack 21 partials, wave-shuffle reduce (wave = 64), combine 4 waves via LDS.
    float vals[21];
    #pragma unroll
    for (int k = 0; k < K_; ++k) {
        vals[k]      = fs[k];
        vals[4 + k]  = in[k];
        vals[8 + k]  = ps[k];
        vals[12 + k] = i2[k];
        vals[16 + k] = ms[k];
    }
    vals[20] = ts;

    #pragma unroll
    for (int v = 0; v < 21; ++v) {
        float x = vals[v];
        #pragma unroll
        for (int off = 32; off > 0; off >>= 1) x += __shfl_down(x, off, 64);
        vals[v] = x;
    }

    __shared__ float smem[21 * 4];
    __syncthreads();                         // lds buffers done; reuse smem area safely
    if (lane == 0) {
        #pragma unroll
        for (int v = 0; v < 21; ++v) smem[v * 4 + wave] = vals[v];
    }
    __syncthreads();

    if (tid < 21) {
        const int v = tid;
        const float x = smem[v * 4 + 0] + smem[v * 4 + 1] +
                        smem[v * 4 + 2] + smem[v * 4 + 3];
        float* dst;
        if      (v < 4)  dst = &fsum[b * K_ + v];
        else if (v < 8)  dst = &inter[b * K_ + (v - 4)];
        else if (v < 12) dst = &psum[b * K_ + (v - 8)];
        else if (v < 16) dst = &i2s[b * K_ + (v - 12)];
        else if (v < 20) dst = &msum[b * K_ + (v - 16)];
        else             dst = &tsum[b];
        atomicAdd(dst, x);
    }
}

__global__ __launch_bounds__(128) void finalize_kernel(
    const float* __restrict__ pred_ious,    // B*K
    const float* __restrict__ fsum,
    const float* __restrict__ inter,
    const float* __restrict__ psum,
    const float* __restrict__ i2s,
    const float* __restrict__ msum,
    const float* __restrict__ tsum,
    float* __restrict__ out)                // [focal, dice, iou]
{
    const float lo[K_] = {0.00f, 0.01f, 0.09f, 0.25f};
    const float hi[K_] = {0.04f, 0.16f, 0.49f, 1.00f};
    const float SMOOTH = 0.0001f;

    const int b = threadIdx.x;              // 128 threads, one per sample
    const float ts = tsum[b];
    const float ratio = ts * (1.0f / (float)HW_);

    float cnt = 0.f, fA = 0.f, dA = 0.f, iA = 0.f;
    #pragma unroll
    for (int k = 0; k < K_; ++k) {
        const bool valid = (ratio > lo[k]) && (ratio < hi[k]);
        if (valid) {
            cnt += 1.0f;
            fA += fsum[b * K_ + k] * (1.0f / (float)HW_);
            const float in_ = inter[b * K_ + k];
            const float ps_ = psum[b * K_ + k];
            dA += 1.0f - (2.0f * in_ + SMOOTH) / (ps_ + ts + SMOOTH);
            const float i2_ = i2s[b * K_ + k];
            const float ms_ = msum[b * K_ + k];
            const float gt  = (i2_ + SMOOTH) / (ms_ + ts - i2_ + SMOOTH);
            const float d   = pred_ious[b * K_ + k] - gt;
            iA += d * d;
        }
    }
    const float invc = (cnt > 0.f) ? (1.0f / cnt) : 0.0f;
    fA *= invc; dA *= invc; iA *= invc;      // per_sample (0 when cnt==0)
    float vb = (cnt > 0.f) ? 1.0f : 0.0f;

    // Reduce 4 quantities across 128 threads (2 waves).
    float vals[4] = {fA, dA, iA, vb};
    const int lane = threadIdx.x & 63;
    const int wave = threadIdx.x >> 6;
    #pragma unroll
    for (int v = 0; v < 4; ++v) {
        float x = vals[v];
        #pragma unroll
        for (int off = 32; off > 0; off >>= 1) x += __shfl_down(x, off, 64);
        vals[v] = x;
    }
    __shared__ float smem[4 * 2];
    if (lane == 0) {
        #pragma unroll
        for (int v = 0; v < 4; ++v) smem[v * 2 + wave] = vals[v];
    }
    __syncthreads();
    if (threadIdx.x == 0) {
        const float fT  = smem[0] + smem[1];
        const float dT  = smem[2] + smem[3];
        const float iT  = smem[4] + smem[5];
        const float vbT = smem[6] + smem[7];
        const float scale = (vbT > 0.f) ? (1.0f / vbT) : 1.0f;
        out[0] = 20.0f * fT * scale;   // FOCAL_W
        out[1] = dT * scale;           // DICE_W
        out[2] = iT * scale;           // IOU_W
    }
}

extern "C" void kernel_launch(void* const* d_in, const int* in_sizes, int n_in,
                              void* d_out, int out_size, void* d_ws, size_t ws_size,
                              hipStream_t stream) {
    const float* pred_masks = (const float*)d_in[0];   // B*K*HW
    const float* pred_ious  = (const float*)d_in[1];   // B*K
    const float* targets    = (const float*)d_in[2];   // B*HW
    float* out = (float*)d_out;

    float* ws    = (float*)d_ws;
    float* fsum  = ws;            // B*K = 512
    float* inter = ws + 512;
    float* psum  = ws + 1024;
    float* i2s   = ws + 1536;
    float* msum  = ws + 2048;
    float* tsum  = ws + 2560;     // B = 128  -> total 2688 floats

    (void)hipMemsetAsync(d_ws, 0, 2688 * sizeof(float), stream);

    partial_kernel<<<B_ * NC, BLOCK, 0, stream>>>(
        pred_masks, targets, fsum, inter, psum, i2s, msum, tsum);
    finalize_kernel<<<1, 128, 0, stream>>>(
        pred_ious, fsum, inter, psum, i2s, msum, tsum, out);
}

// Round 8
// 215.449 us; speedup vs baseline: 1.0329x; 1.0329x over previous
//
#include <hip/hip_runtime.h>
#include <math.h>

// Problem constants
#define B_   128
#define K_   4
#define HW_  65536              // 256*256

constexpr int BLOCK = 256;
constexpr int NC    = 4;                    // chunks per (b,k) plane
constexpr int CHUNK = HW_ / NC;             // 16384 floats
constexpr int G     = CHUNK / 4 / BLOCK;    // 16 float4-groups per thread

typedef float vfloat4 __attribute__((ext_vector_type(4)));

// Per-element math (t is exactly 0.0 or 1.0):
//   s   = sigmoid(x)
//   pt  = t*s + (1-t)*(1-s) = fma(t, 1-2s, s)   (true-class probability)
//   bce = -ln(pt); exp(-bce) == pt
//   focal += ALPHA * (1-pt)^2 * bce
// Native v_exp/v_rcp/v_log — rel err ~1e-6, threshold is 0.11.
__device__ __forceinline__ void proc_elem(float x, float t,
                                          float& fs, float& in, float& ps,
                                          float& i2, float& ms) {
    float e   = __expf(-fabsf(x));                 // e^{-|x|}
    float inv = __builtin_amdgcn_rcpf(1.0f + e);   // sigmoid(|x|)
    bool  pos = (x >= 0.0f);
    float s   = pos ? inv : 1.0f - inv;            // sigmoid(x)
    float nms = fmaf(-2.0f, s, 1.0f);              // 1 - 2s
    float pt  = fmaf(t, nms, s);                   // prob of true class
    float l   = __logf(pt);                        // ln(pt) = -bce
    float om  = 1.0f - pt;
    fs = fmaf(om * om * l, -0.8f, fs);             // += ALPHA*(1-pt)^2*bce
    float pc  = fminf(fmaxf(s, 1e-4f), 0.9999f);   // clip(sigmoid) -> v_med3
    ps += pc;
    in  = fmaf(pc, t, in);
    float m = pos ? 1.0f : 0.0f;                   // mask (x >= 0)
    ms += m;
    i2  = fmaf(m, t, i2);
}

__device__ __forceinline__ void proc4(const vfloat4& xv, const vfloat4& tv,
                                      float& fs, float& in, float& ps,
                                      float& i2, float& ms, float& ts) {
    proc_elem(xv.x, tv.x, fs, in, ps, i2, ms);
    proc_elem(xv.y, tv.y, fs, in, ps, i2, ms);
    proc_elem(xv.z, tv.z, fs, in, ps, i2, ms);
    proc_elem(xv.w, tv.w, fs, in, ps, i2, ms);
    ts += tv.x + tv.y + tv.z + tv.w;
}

// Split-K, DEPTH-4 rotating register pipeline. Load-to-use distance is 3
// compute phases (~650+ cyc) so in-flight loads cover HBM latency; 8 vfloat4
// buffers (32 VGPR) + 6 acc + addressing ≈ 55 VGPR fits the (256,6) cap of
// 85 with slack (no spill, no forced load serialization). 24 waves/CU.
// '#pragma unroll 1' keeps the rotation intact (3 real iterations at NC=4).
// Masks: nontemporal (zero reuse). Targets: plain loads (k-siblings reuse).
// XCD swizzle: with round-robin dispatch (blk % 8 -> XCD), map so all 4
// k-siblings of one (b,c) target chunk land on ONE XCD -> 3 of 4 target
// reads become that XCD's L2 hits. Heuristic only — correctness unaffected.
__global__ __launch_bounds__(BLOCK, 6) void partial_kernel(
    const float* __restrict__ pred_masks,   // B*K*HW
    const float* __restrict__ targets,      // B*HW
    float* __restrict__ fsum,               // B*K
    float* __restrict__ inter,              // B*K
    float* __restrict__ psum,               // B*K
    float* __restrict__ i2s,                // B*K
    float* __restrict__ msum,               // B*K
    float* __restrict__ tsum)               // B  (accumulated K_ times)
{
    // 2048 blocks: xcd slot = blk&7, seq = blk>>3 (256 per XCD).
    // k fastest within seq so one XCD sees (pair, k=0..3) back-to-back.
    const int xcd  = blockIdx.x & 7;
    const int seq  = blockIdx.x >> 3;
    const int k    = seq & (K_ - 1);
    const int pair = xcd * 64 + (seq >> 2);  // 512 (b,c) pairs, 64 per XCD
    const int b    = pair >> 2;              // NC == 4
    const int c    = pair & (NC - 1);

    const vfloat4* __restrict__ t4 =
        reinterpret_cast<const vfloat4*>(targets + (size_t)b * HW_ + c * CHUNK);
    const vfloat4* __restrict__ x4 =
        reinterpret_cast<const vfloat4*>(pred_masks +
            ((size_t)(b * K_ + k)) * HW_ + c * CHUNK);

    float fs = 0.f, in = 0.f, ps = 0.f, i2 = 0.f, ms = 0.f, ts = 0.f;

    int idx = threadIdx.x;
    // Preload groups 0..3 into rotating buffers A..D.
    vfloat4 tA = t4[idx];
    vfloat4 xA = __builtin_nontemporal_load(&x4[idx]);
    vfloat4 tB = t4[idx + BLOCK];
    vfloat4 xB = __builtin_nontemporal_load(&x4[idx + BLOCK]);
    vfloat4 tC = t4[idx + 2 * BLOCK];
    vfloat4 xC = __builtin_nontemporal_load(&x4[idx + 2 * BLOCK]);
    vfloat4 tD = t4[idx + 3 * BLOCK];
    vfloat4 xD = __builtin_nontemporal_load(&x4[idx + 3 * BLOCK]);

    #pragma unroll 1
    for (int g = 0; g + 4 < G; g += 4) {    // g = 0,4,8 -> 3 iterations
        proc4(xA, tA, fs, in, ps, i2, ms, ts);
        tA = t4[idx + 4 * BLOCK];
        xA = __builtin_nontemporal_load(&x4[idx + 4 * BLOCK]);
        proc4(xB, tB, fs, in, ps, i2, ms, ts);
        tB = t4[idx + 5 * BLOCK];
        xB = __builtin_nontemporal_load(&x4[idx + 5 * BLOCK]);
        proc4(xC, tC, fs, in, ps, i2, ms, ts);
        tC = t4[idx + 6 * BLOCK];
        xC = __builtin_nontemporal_load(&x4[idx + 6 * BLOCK]);
        proc4(xD, tD, fs, in, ps, i2, ms, ts);
        tD = t4[idx + 7 * BLOCK];
        xD = __builtin_nontemporal_load(&x4[idx + 7 * BLOCK]);
        idx += 4 * BLOCK;
    }
    // Epilogue: compute final 4 groups (12..15).
    proc4(xA, tA, fs, in, ps, i2, ms, ts);
    proc4(xB, tB, fs, in, ps, i2, ms, ts);
    proc4(xC, tC, fs, in, ps, i2, ms, ts);
    proc4(xD, tD, fs, in, ps, i2, ms, ts);

    // Reduce 6 partials: wave shuffle (64 lanes) -> LDS across 4 waves -> atomic.
    float vals[6] = {fs, in, ps, i2, ms, ts};
    const int lane = threadIdx.x & 63;
    const int wave = threadIdx.x >> 6;

    #pragma unroll
    for (int v = 0; v < 6; ++v) {
        float x = vals[v];
        #pragma unroll
        for (int off = 32; off > 0; off >>= 1) x += __shfl_down(x, off, 64);
        vals[v] = x;
    }

    __shared__ float smem[6 * 4];
    if (lane == 0) {
        #pragma unroll
        for (int v = 0; v < 6; ++v) smem[v * 4 + wave] = vals[v];
    }
    __syncthreads();

    if (threadIdx.x < 6) {
        const int v = threadIdx.x;
        const float x = smem[v * 4 + 0] + smem[v * 4 + 1] +
                        smem[v * 4 + 2] + smem[v * 4 + 3];
        const int bk = b * K_ + k;
        float* dst;
        if      (v == 0) dst = &fsum[bk];
        else if (v == 1) dst = &inter[bk];
        else if (v == 2) dst = &psum[bk];
        else if (v == 3) dst = &i2s[bk];
        else if (v == 4) dst = &msum[bk];
        else             dst = &tsum[b];    // summed by all K_ k-blocks
        atomicAdd(dst, x);
    }
}

__global__ __launch_bounds__(128) void finalize_kernel(
    const float* __restrict__ pred_ious,    // B*K
    const float* __restrict__ fsum,
    const float* __restrict__ inter,
    const float* __restrict__ psum,
    const float* __restrict__ i2s,
    const float* __restrict__ msum,
    const float* __restrict__ tsum,
    float* __restrict__ out)                // [focal, dice, iou]
{
    const float lo[K_] = {0.00f, 0.01f, 0.09f, 0.25f};
    const float hi[K_] = {0.04f, 0.16f, 0.49f, 1.00f};
    const float SMOOTH = 0.0001f;

    const int b = threadIdx.x;              // 128 threads, one per sample
    const float ts = tsum[b] * 0.25f;       // undo K_-fold accumulation
    const float ratio = ts * (1.0f / (float)HW_);

    float cnt = 0.f, fA = 0.f, dA = 0.f, iA = 0.f;
    #pragma unroll
    for (int k = 0; k < K_; ++k) {
        const bool valid = (ratio > lo[k]) && (ratio < hi[k]);
        if (valid) {
            cnt += 1.0f;
            fA += fsum[b * K_ + k] * (1.0f / (float)HW_);
            const float in_ = inter[b * K_ + k];
            const float ps_ = psum[b * K_ + k];
            dA += 1.0f - (2.0f * in_ + SMOOTH) / (ps_ + ts + SMOOTH);
            const float i2_ = i2s[b * K_ + k];
            const float ms_ = msum[b * K_ + k];
            const float gt  = (i2_ + SMOOTH) / (ms_ + ts - i2_ + SMOOTH);
            const float d   = pred_ious[b * K_ + k] - gt;
            iA += d * d;
        }
    }
    const float invc = (cnt > 0.f) ? (1.0f / cnt) : 0.0f;
    fA *= invc; dA *= invc; iA *= invc;      // per_sample (0 when cnt==0)
    float vb = (cnt > 0.f) ? 1.0f : 0.0f;

    // Reduce 4 quantities across 128 threads (2 waves).
    float vals[4] = {fA, dA, iA, vb};
    const int lane = threadIdx.x & 63;
    const int wave = threadIdx.x >> 6;
    #pragma unroll
    for (int v = 0; v < 4; ++v) {
        float x = vals[v];
        #pragma unroll
        for (int off = 32; off > 0; off >>= 1) x += __shfl_down(x, off, 64);
        vals[v] = x;
    }
    __shared__ float smem[4 * 2];
    if (lane == 0) {
        #pragma unroll
        for (int v = 0; v < 4; ++v) smem[v * 2 + wave] = vals[v];
    }
    __syncthreads();
    if (threadIdx.x == 0) {
        const float fT  = smem[0] + smem[1];
        const float dT  = smem[2] + smem[3];
        const float iT  = smem[4] + smem[5];
        const float vbT = smem[6] + smem[7];
        const float scale = (vbT > 0.f) ? (1.0f / vbT) : 1.0f;
        out[0] = 20.0f * fT * scale;   // FOCAL_W
        out[1] = dT * scale;           // DICE_W
        out[2] = iT * scale;           // IOU_W
    }
}

extern "C" void kernel_launch(void* const* d_in, const int* in_sizes, int n_in,
                              void* d_out, int out_size, void* d_ws, size_t ws_size,
                              hipStream_t stream) {
    const float* pred_masks = (const float*)d_in[0];   // B*K*HW
    const float* pred_ious  = (const float*)d_in[1];   // B*K
    const float* targets    = (const float*)d_in[2];   // B*HW
    float* out = (float*)d_out;

    float* ws    = (float*)d_ws;
    float* fsum  = ws;            // B*K = 512
    float* inter = ws + 512;
    float* psum  = ws + 1024;
    float* i2s   = ws + 1536;
    float* msum  = ws + 2048;
    float* tsum  = ws + 2560;     // B = 128  -> total 2688 floats

    (void)hipMemsetAsync(d_ws, 0, 2688 * sizeof(float), stream);

    partial_kernel<<<B_ * NC * K_, BLOCK, 0, stream>>>(
        pred_masks, targets, fsum, inter, psum, i2s, msum, tsum);
    finalize_kernel<<<1, 128, 0, stream>>>(
        pred_ious, fsum, inter, psum, i2s, msum, tsum, out);
}